// Round 5
// baseline (17.930 us; speedup 1.0000x reference)
//
#include <hip/hip_runtime.h>

#define WORD_LEN 16
#define BLOCK 256

// (256, 8): 8 waves/SIMD; live state ~45 VGPRs, fits 64 comfortably.
__global__ __launch_bounds__(BLOCK, 8) void oct_word_emb_kernel(
    const int* __restrict__ ids,
    const float* __restrict__ emb,
    float* __restrict__ out)
{
    // Embedding imag parts, 16B rows (round-4 layout: 2x ds_read_b128/char).
    __shared__ float4 slo[256];   // imag 1..4
    __shared__ float4 shi[256];   // imag 5..7 + pad
    // Packed ids: dword n holds ids[4n..4n+3] of this block (ids < 256 fit bytes).
    // Write: lane-linear ds_write_b32 (conflict-free). Read: thread t ds_read_b128
    // at dword 4t: 8 lanes per 4-bank group x 4 dwords = 8/bank = pass floor.
    __shared__ __align__(16) unsigned int sids[BLOCK * 4];   // 4 KB

    const int tid = threadIdx.x;

    // ---- stage embedding: thread t handles row t (vocab = 256 = blockDim) ----
    {
        const float4* e4 = reinterpret_cast<const float4*>(emb);
        float4 lo = e4[tid * 2 + 0];   // emb[t][0..3]
        float4 hi = e4[tid * 2 + 1];   // emb[t][4..7]
        slo[tid] = make_float4(lo.y, lo.z, lo.w, hi.x);
        shi[tid] = make_float4(hi.y, hi.z, hi.w, 0.0f);
    }

    // ---- coalesced id staging: 4x int4/thread, lane-contiguous (1KB bursts) ----
    {
        const int4* g = reinterpret_cast<const int4*>(ids) + (size_t)blockIdx.x * (BLOCK * 4);
        #pragma unroll
        for (int j = 0; j < 4; ++j) {
            int4 w = g[j * BLOCK + tid];   // int4 #(j*256+tid) = ids[4n..4n+3]
            sids[j * BLOCK + tid] = (unsigned)w.x | ((unsigned)w.y << 8) |
                                    ((unsigned)w.z << 16) | ((unsigned)w.w << 24);
        }
    }
    __syncthreads();

    // One b128: thread t's 16 ids, packed 4/dword.
    const uint4 pid = reinterpret_cast<const uint4*>(sids)[tid];
    const unsigned pw[4] = {pid.x, pid.y, pid.z, pid.w};

    float v[7];
    {
        const unsigned id0 = pw[0] & 0xff;
        const float4 a = slo[id0];
        const float4 h = shi[id0];
        v[0] = a.x; v[1] = a.y; v[2] = a.z; v[3] = a.w;
        v[4] = h.x; v[5] = h.y; v[6] = h.z;
    }

    // Fano triples (0-indexed). cross(a,b) per triple (i,j,k):
    //   r[k] += a[i]b[j] - a[j]b[i];  r[i] += a[j]b[k] - a[k]b[j];  r[j] += a[k]b[i] - a[i]b[k]
    #pragma unroll
    for (int t = 1; t < WORD_LEN; ++t) {
        const unsigned idt = (pw[t >> 2] >> ((t & 3) * 8)) & 0xff;   // constant shifts
        const float4 a = slo[idt];
        const float4 h = shi[idt];
        const float x[7] = {a.x, a.y, a.z, a.w, h.x, h.y, h.z};

        float r[7] = {0.f, 0.f, 0.f, 0.f, 0.f, 0.f, 0.f};
        constexpr int TRI[7][3] = {{0,1,2},{0,3,4},{0,6,5},{1,3,5},{1,4,6},{2,3,6},{2,5,4}};
        #pragma unroll
        for (int q = 0; q < 7; ++q) {
            const int i = TRI[q][0], j = TRI[q][1], k = TRI[q][2];
            r[k] = fmaf(v[i], x[j], r[k]);  r[k] = fmaf(-v[j], x[i], r[k]);
            r[i] = fmaf(v[j], x[k], r[i]);  r[i] = fmaf(-v[k], x[j], r[i]);
            r[j] = fmaf(v[k], x[i], r[j]);  r[j] = fmaf(-v[i], x[k], r[j]);
        }
        #pragma unroll
        for (int c = 0; c < 7; ++c) v[c] = r[c];
    }

    // Scalar stores (round 2 proved staging these is worth +-0; writes are
    // fire-and-forget, no read amplification).
    float* o = out + ((size_t)blockIdx.x * BLOCK + tid) * 7;
    #pragma unroll
    for (int c = 0; c < 7; ++c) o[c] = v[c];
}

extern "C" void kernel_launch(void* const* d_in, const int* in_sizes, int n_in,
                              void* d_out, int out_size, void* d_ws, size_t ws_size,
                              hipStream_t stream) {
    const int* ids = (const int*)d_in[0];      // (524288, 16) int32
    const float* emb = (const float*)d_in[1];  // (256, 8) fp32
    float* out = (float*)d_out;                // (524288, 7) fp32

    const int batch = in_sizes[0] / WORD_LEN;  // 524288
    const int grid = batch / BLOCK;            // 2048

    oct_word_emb_kernel<<<grid, BLOCK, 0, stream>>>(ids, emb, out);
}